// Round 9
// baseline (175.140 us; speedup 1.0000x reference)
//
#include <hip/hip_runtime.h>

typedef __attribute__((ext_vector_type(8))) short bf16x8;
typedef __attribute__((ext_vector_type(4))) float f32x4;

__device__ __forceinline__ unsigned short f2bf(float f){
  union { float f; unsigned int u; } v; v.f = f;
  unsigned int u = v.u;
  return (unsigned short)((u + 0x7FFFu + ((u >> 16) & 1u)) >> 16);  // RNE
}

__device__ __forceinline__ float fast_tanh(float x){
  x = fminf(15.f, fmaxf(-15.f, x));
  float e = __expf(2.f * x);
  return (e - 1.f) / (e + 1.f);
}

__device__ __forceinline__ float dot128(const float* __restrict__ a,
                                        const float* __restrict__ b){
  float s = 0.f;
  for (int c = 0; c < 128; c += 4){
    float4 x = *(const float4*)(a + c);
    float4 y = *(const float4*)(b + c);
    s += x.x*y.x + x.y*y.y + x.z*y.z + x.w*y.w;
  }
  return s;
}

#define GRPSUM(x) { x += __shfl_xor(x, 1); x += __shfl_xor(x, 2); \
                    x += __shfl_xor(x, 4); x += __shfl_xor(x, 8); }

// one consumer lane per flag; producer is earlier in dispatch order
__device__ __forceinline__ void wait_flag(const int* p){
  if ((threadIdx.x & 63) == 0){
    while (__hip_atomic_load(p, __ATOMIC_RELAXED, __HIP_MEMORY_SCOPE_AGENT) == 0)
      __builtin_amdgcn_s_sleep(2);
  }
  __threadfence();   // acquire
}

// ws float layout:
//   f[0 .. 6144)    : Bpack  — MFMA1 B-frags (12288 bf16), layer-1 weights
//   f[6144 .. 6912) : B2pack — MFMA2' B-frags (1536 bf16): 3 tiles
//   f[6912 .. 6944) : u'[h]   f[6944..6976): wv[h]
//   f[6976] = rs*(bk2.bq2)    f[6977] = bv2.Wval[0:128]
//   int flags at f[8192]  (B ints, zeroed by k0)
//   f[10256 .. )    : ws_ov[B*16]

// ---------------------------------------------------------------------------
// k0: tables + zero per-batch flags
// ---------------------------------------------------------------------------
__global__ __launch_bounds__(64) void k0_kernel(
    const float* __restrict__ Wk1, const float* __restrict__ Wq1, const float* __restrict__ Wv1,
    const float* __restrict__ Wk2, const float* __restrict__ bk2,
    const float* __restrict__ Wq2, const float* __restrict__ bq2,
    const float* __restrict__ Wv2, const float* __restrict__ bv2,
    const float* __restrict__ Wval, float* __restrict__ ws, int B)
{
  const int tid = blockIdx.x * 64 + threadIdx.x;  // 0..4095
  const float rs = 0.08838834764831845f;          // 1/sqrt(128)
  unsigned short* bp = (unsigned short*)ws;
  unsigned short* b2 = (unsigned short*)(ws + 6144);

  if (tid < 1536){
    const int e = tid & 7, l = (tid >> 3) & 63, tt = tid >> 9;
    const int g = (l >> 4) * 8 + e;
    float val = 0.f;
    if (tt < 2){
      const int h = (l & 15) + tt * 16;
      val = rs * dot128(Wk2 + h * 128, Wq2 + g * 128);
    } else if ((l & 15) == 0){
      val = rs * dot128(Wq2 + g * 128, bk2);
    }
    b2[tid] = f2bf(val);
  } else if (tid < 1600){
    const int h = tid - 1536;
    if (h < 32) ws[6912 + h] = rs * dot128(Wk2 + h * 128, bq2);
    else        ws[6944 + (h - 32)] = dot128(Wv2 + (h - 32) * 128, Wval);
  } else if (tid == 1600){
    ws[6976] = rs * dot128(bk2, bq2);
  } else if (tid == 1601){
    ws[6977] = dot128(bv2, Wval);
  }

  for (int idx = tid; idx < 12288; idx += 4096){
    const int e  = idx & 7;
    const int l  = (idx >> 3) & 63;
    const int kc = (idx >> 9) & 3;
    const int nt = (idx >> 11) & 1;
    const int m  = idx >> 12;
    const float* W1 = (m == 0) ? Wk1 : ((m == 1) ? Wq1 : Wv1);
    const int krow = kc * 32 + (l >> 4) * 8 + e;
    const int col  = nt * 16 + (l & 15);
    bp[idx] = f2bf(W1[krow * 32 + col]);
  }

  // zero flags
  int* flags = (int*)(ws + 8192);
  if (tid < B) flags[tid] = 0;
}

// ---------------------------------------------------------------------------
// mega: interleaved specialization. bid%5==0 -> attention group g=bid/5
// (4 batches, wave per batch; writes alpha + ws_ov + per-batch flag).
// Else -> noise batch b = (bid/5)*4 + bid%5 - 1 (streams, waits ITS flag,
// writes final out_x). Producer bid < consumer bid.
// ---------------------------------------------------------------------------
__global__ __launch_bounds__(256) void mega_kernel(
    const float* __restrict__ obs,
    const float* __restrict__ policies, const float* __restrict__ actions,
    const float* __restrict__ noise, const float* __restrict__ weights,
    const float* __restrict__ bk1p, const float* __restrict__ bq1p, const float* __restrict__ bv1p,
    const float* __restrict__ Wval, const float* __restrict__ bval,
    float* ws, float* __restrict__ out_x, float* __restrict__ out_alpha)
{
  int*   flags = (int*)(ws + 8192);
  float* ws_ov = ws + 10256;
  const int t = threadIdx.x;
  const int bid = blockIdx.x;
  const int g = bid / 5, k5 = bid - g * 5;

  if (k5 == 0){
    // ===================== attention block: batches 4g..4g+3 ================
    __shared__ __align__(16) unsigned short hk_s[4][512];
    __shared__ __align__(16) unsigned short hq_s[4][512];
    __shared__ __align__(16) unsigned short tq_s[4][512];
    __shared__ __align__(16) float rql_s[4][16];
    __shared__ __align__(16) float vvl_s[4][16];

    const int wid = t >> 6, l = t & 63;
    const int b = g * 4 + wid;
    const int li = l & 15, gp = l >> 4;

    const float* orow = obs + (size_t)(b * 16 + li) * 128 + gp * 8;
    float4 ob[8];
#pragma unroll
    for (int kc = 0; kc < 4; kc++){
      ob[kc * 2]     = *(const float4*)(orow + kc * 32);
      ob[kc * 2 + 1] = *(const float4*)(orow + kc * 32 + 4);
    }

    const bf16x8* bp  = (const bf16x8*)ws;
    const bf16x8* b2p = (const bf16x8*)(ws + 6144);
    const bf16x8 b20 = b2p[l], b21 = b2p[64 + l], b22 = b2p[128 + l];
    const float u0 = ws[6912 + li], u1 = ws[6928 + li];
    const float wv0 = ws[6944 + li], wv1 = ws[6960 + li];
    const float ccv = ws[6976], cvv = ws[6977];
    const float bk0 = bk1p[li], bk1v = bk1p[16 + li];
    const float bq0 = bq1p[li], bq1v = bq1p[16 + li];
    const float bv0 = bv1p[li], bv1v = bv1p[16 + li];

    bf16x8 afr[4];
#pragma unroll
    for (int kc = 0; kc < 4; kc++){
      bf16x8 a;
      a[0]=(short)f2bf(ob[kc*2].x); a[1]=(short)f2bf(ob[kc*2].y);
      a[2]=(short)f2bf(ob[kc*2].z); a[3]=(short)f2bf(ob[kc*2].w);
      a[4]=(short)f2bf(ob[kc*2+1].x); a[5]=(short)f2bf(ob[kc*2+1].y);
      a[6]=(short)f2bf(ob[kc*2+1].z); a[7]=(short)f2bf(ob[kc*2+1].w);
      afr[kc] = a;
    }
    f32x4 acc[6];
#pragma unroll
    for (int mt = 0; mt < 6; mt++){ f32x4 z = {0.f,0.f,0.f,0.f}; acc[mt] = z; }
#pragma unroll
    for (int mt = 0; mt < 6; mt++){
#pragma unroll
      for (int kc = 0; kc < 4; kc++)
        acc[mt] = __builtin_amdgcn_mfma_f32_16x16x32_bf16(afr[kc], bp[(mt*4+kc)*64 + l], acc[mt], 0, 0, 0);
    }

    unsigned short* hkb = hk_s[wid];
    unsigned short* hqb = hq_s[wid];
#pragma unroll
    for (int tile = 0; tile < 2; tile++){
      const float bk_ = tile ? bk1v : bk0;
      const float bq_ = tile ? bq1v : bq0;
      f32x4 ck = acc[tile], cq = acc[2 + tile];
#pragma unroll
      for (int r = 0; r < 4; r++){
        hkb[(gp*4+r)*32 + tile*16 + li] = f2bf(fast_tanh(ck[r] + bk_));
        hqb[(gp*4+r)*32 + tile*16 + li] = f2bf(fast_tanh(cq[r] + bq_));
      }
    }

    { // vv[j] = wv . tanh(h_v[j]) + cv
      f32x4 c0 = acc[4], c1 = acc[5];
      float vp0 = wv0*fast_tanh(c0[0]+bv0) + wv1*fast_tanh(c1[0]+bv1v);
      float vp1 = wv0*fast_tanh(c0[1]+bv0) + wv1*fast_tanh(c1[1]+bv1v);
      float vp2 = wv0*fast_tanh(c0[2]+bv0) + wv1*fast_tanh(c1[2]+bv1v);
      float vp3 = wv0*fast_tanh(c0[3]+bv0) + wv1*fast_tanh(c1[3]+bv1v);
      GRPSUM(vp0); GRPSUM(vp1); GRPSUM(vp2); GRPSUM(vp3);
      if (li == 0){
        float4 vq; vq.x = vp0+cvv; vq.y = vp1+cvv; vq.z = vp2+cvv; vq.w = vp3+cvv;
        *(float4*)&vvl_s[wid][gp*4] = vq;
      }
    }

    // MFMA2': tq = hq.(rs*M^T) + rs*u ; tile2 -> rs*(rq + cc)
    const bf16x8 aq = *(const bf16x8*)(hqb + li*32 + gp*8);
    f32x4 cu0 = {u0,u0,u0,u0}, cu1 = {u1,u1,u1,u1}, cu2 = {ccv,ccv,ccv,ccv};
    f32x4 tq0 = __builtin_amdgcn_mfma_f32_16x16x32_bf16(aq, b20, cu0, 0, 0, 0);
    f32x4 tq1 = __builtin_amdgcn_mfma_f32_16x16x32_bf16(aq, b21, cu1, 0, 0, 0);
    f32x4 rqt = __builtin_amdgcn_mfma_f32_16x16x32_bf16(aq, b22, cu2, 0, 0, 0);
    if (li == 0){
      float4 rv; rv.x = rqt[0]; rv.y = rqt[1]; rv.z = rqt[2]; rv.w = rqt[3];
      *(float4*)&rql_s[wid][gp*4] = rv;
    }
    unsigned short* tqb = tq_s[wid];
#pragma unroll
    for (int r = 0; r < 4; r++){
      tqb[(gp*4+r)*32 + li]      = f2bf(tq0[r]);
      tqb[(gp*4+r)*32 + 16 + li] = f2bf(tq1[r]);
    }

    // MFMA3: S[j][i] = hk[j] . tq[i]
    const bf16x8 ak = *(const bf16x8*)(hkb + li*32 + gp*8);
    const bf16x8 bt = *(const bf16x8*)(tqb + li*32 + gp*8);
    f32x4 zz = {0.f,0.f,0.f,0.f};
    f32x4 S = __builtin_amdgcn_mfma_f32_16x16x32_bf16(ak, bt, zz, 0, 0, 0);
    const float rc = rql_s[wid][li];
    float s0 = S[0]+rc, s1 = S[1]+rc, s2 = S[2]+rc, s3 = S[3]+rc;

    // softmax over senders j
    float mx = fmaxf(fmaxf(s0, s1), fmaxf(s2, s3));
    mx = fmaxf(mx, __shfl_xor(mx, 16)); mx = fmaxf(mx, __shfl_xor(mx, 32));
    float e0 = __expf(s0-mx), e1 = __expf(s1-mx), e2 = __expf(s2-mx), e3 = __expf(s3-mx);
    float sm = e0+e1+e2+e3;
    sm += __shfl_xor(sm, 16); sm += __shfl_xor(sm, 32);
    const float inv = 1.f / sm;
    const float a0 = e0*inv, a1 = e1*inv, a2 = e2*inv, a3 = e3*inv;

    // alpha out via LDS transpose
    float* aT = (float*)tqb;
    { float4 av4; av4.x = a0; av4.y = a1; av4.z = a2; av4.w = a3;
      *(float4*)&aT[li*16 + gp*4] = av4; }
    { float4 o4 = *(const float4*)&aT[l*4];
      *(float4*)(out_alpha + (size_t)b*256 + l*4) = o4; }

    // ov[i] = sum_j alpha[i][j] * vv[j]  -> ws_ov, then release flag
    float4 vq4 = *(const float4*)&vvl_s[wid][gp*4];
    float ovp = a0*vq4.x + a1*vq4.y + a2*vq4.z + a3*vq4.w;
    ovp += __shfl_xor(ovp, 16); ovp += __shfl_xor(ovp, 32);
    if (l < 16) ws_ov[(size_t)b*16 + l] = ovp;
    __threadfence();
    if (l == 0)
      __hip_atomic_store(flags + b, 1, __ATOMIC_RELEASE, __HIP_MEMORY_SCOPE_AGENT);
    return;
  }

  // ===================== noise block: batch b = g*4 + k5-1 =================
  {
    __shared__ __align__(16) float nvw[256];
    __shared__ __align__(16) float pvl[16], avl[16];

    const int b = g * 4 + k5 - 1;
    const int w = t >> 6, l = t & 63;
    const int q8 = l & 7, r8 = l >> 3;
    const float4 wv4 = *(const float4*)(Wval + 128 + q8 * 4);

    float4 pA0, pA1, aA0, aA1, wpa, wpb;
    const int jp = l >> 2, seg = l & 3;
    if (w == 0){
      const float* pp = policies + (size_t)(b * 16 + jp) * 32 + seg * 8;
      const float* ap = actions  + (size_t)(b * 16 + jp) * 32 + seg * 8;
      pA0 = *(const float4*)(pp);
      pA1 = *(const float4*)(pp + 4);
      aA0 = *(const float4*)(ap);
      aA1 = *(const float4*)(ap + 4);
      wpa = *(const float4*)(Wval + 128 + seg * 8);
      wpb = *(const float4*)(Wval + 132 + seg * 8);
    }

    // 64 rows per wave, 8 up-front float4 loads per lane
    const float* nbl = noise + (size_t)b * 8192 + (w * 64 + r8) * 32 + q8 * 4;
    float4 nz[8];
#pragma unroll
    for (int p = 0; p < 8; p++) nz[p] = *(const float4*)(nbl + p * 256);
#pragma unroll
    for (int p = 0; p < 8; p++){
      float s = nz[p].x*wv4.x + nz[p].y*wv4.y + nz[p].z*wv4.z + nz[p].w*wv4.w;
      s += __shfl_xor(s, 1); s += __shfl_xor(s, 2); s += __shfl_xor(s, 4);
      if (q8 == 0) nvw[w * 64 + p * 8 + r8] = s;
    }

    if (w == 0){
      float pvv = pA0.x*wpa.x + pA0.y*wpa.y + pA0.z*wpa.z + pA0.w*wpa.w
                + pA1.x*wpb.x + pA1.y*wpb.y + pA1.z*wpb.z + pA1.w*wpb.w;
      float avv = aA0.x*wpa.x + aA0.y*wpa.y + aA0.z*wpa.z + aA0.w*wpa.w
                + aA1.x*wpb.x + aA1.y*wpb.y + aA1.z*wpb.z + aA1.w*wpb.w;
      pvv += __shfl_xor(pvv, 1); pvv += __shfl_xor(pvv, 2);
      avv += __shfl_xor(avv, 1); avv += __shfl_xor(avv, 2);
      if (seg == 0){ pvl[jp] = pvv; avl[jp] = avv; }
    }

    __syncthreads();

    if (w == 0){
      wait_flag(flags + b);   // producer at bid = 5g < this bid
      const float wscal = weights[0];
      const float bvs = bval[0];
      const int i = l >> 2, j0 = (l & 3) * 4;
      float4 pv4 = *(const float4*)&pvl[j0];
      float4 av4 = *(const float4*)&avl[j0];
      float4 nv4 = *(const float4*)&nvw[i * 16 + j0];
      float4 ov4 = *(const float4*)&ws_ov[(size_t)b * 16 + j0];
      const float om = 1.f - wscal;
      float z0 = wscal * av4.x + om * pv4.x + nv4.x;
      float z1 = wscal * av4.y + om * pv4.y + nv4.y;
      float z2 = wscal * av4.z + om * pv4.z + nv4.z;
      float z3 = wscal * av4.w + om * pv4.w + nv4.w;
      float zs = z0 + z1 + z2 + z3;
      zs += __shfl_xor(zs, 1); zs += __shfl_xor(zs, 2);  // over 16 senders j
      float4 o;
      o.x = ov4.x + (pv4.x - z0 + zs) * 0.0625f + bvs;
      o.y = ov4.y + (pv4.y - z1 + zs) * 0.0625f + bvs;
      o.z = ov4.z + (pv4.z - z2 + zs) * 0.0625f + bvs;
      o.w = ov4.w + (pv4.w - z3 + zs) * 0.0625f + bvs;
      *(float4*)(out_x + (size_t)b * 256 + l * 4) = o;
    }
  }
}

// ---------------------------------------------------------------------------
extern "C" void kernel_launch(void* const* d_in, const int* in_sizes, int n_in,
                              void* d_out, int out_size, void* d_ws, size_t ws_size,
                              hipStream_t stream)
{
  const float* obs      = (const float*)d_in[0];
  const float* policies = (const float*)d_in[1];
  const float* actions  = (const float*)d_in[2];
  const float* weights  = (const float*)d_in[3];
  const float* noise    = (const float*)d_in[4];
  const float* Wk1  = (const float*)d_in[5];
  const float* bk1  = (const float*)d_in[6];
  const float* Wk2  = (const float*)d_in[7];
  const float* bk2  = (const float*)d_in[8];
  const float* Wq1  = (const float*)d_in[9];
  const float* bq1  = (const float*)d_in[10];
  const float* Wq2  = (const float*)d_in[11];
  const float* bq2  = (const float*)d_in[12];
  const float* Wv1  = (const float*)d_in[13];
  const float* bv1  = (const float*)d_in[14];
  const float* Wv2  = (const float*)d_in[15];
  const float* bv2  = (const float*)d_in[16];
  const float* Wval = (const float*)d_in[17];
  const float* bval = (const float*)d_in[18];

  float* out = (float*)d_out;
  float* ws  = (float*)d_ws;

  const int NODES = in_sizes[0] / 128;
  const int B = NODES / 16;
  const int BA = B / 4;

  float* out_x     = out;
  float* out_alpha = out + (size_t)NODES * 16;

  hipLaunchKernelGGL(k0_kernel, dim3(64), dim3(64), 0, stream,
                     Wk1, Wq1, Wv1, Wk2, bk2, Wq2, bq2, Wv2, bv2, Wval, ws, B);
  hipLaunchKernelGGL(mega_kernel, dim3(BA * 5), dim3(256), 0, stream,
                     obs, policies, actions, noise, weights,
                     bk1, bq1, bv1, Wval, bval,
                     ws, out_x, out_alpha);
}

// Round 10
// 71.841 us; speedup vs baseline: 2.4379x; 2.4379x over previous
//
#include <hip/hip_runtime.h>

typedef __attribute__((ext_vector_type(8))) short bf16x8;
typedef __attribute__((ext_vector_type(4))) float f32x4;

__device__ __forceinline__ unsigned short f2bf(float f){
  union { float f; unsigned int u; } v; v.f = f;
  unsigned int u = v.u;
  return (unsigned short)((u + 0x7FFFu + ((u >> 16) & 1u)) >> 16);  // RNE
}

__device__ __forceinline__ float fast_tanh(float x){
  x = fminf(15.f, fmaxf(-15.f, x));
  float e = __expf(2.f * x);
  return (e - 1.f) / (e + 1.f);
}

__device__ __forceinline__ float dot128(const float* __restrict__ a,
                                        const float* __restrict__ b){
  float s = 0.f;
  for (int c = 0; c < 128; c += 4){
    float4 x = *(const float4*)(a + c);
    float4 y = *(const float4*)(b + c);
    s += x.x*y.x + x.y*y.y + x.z*y.z + x.w*y.w;
  }
  return s;
}

#define GRPSUM(x) { x += __shfl_xor(x, 1); x += __shfl_xor(x, 2); \
                    x += __shfl_xor(x, 4); x += __shfl_xor(x, 8); }

// ---------------------------------------------------------------------------
// KA: attention, 512 blocks x 4 waves (wave = batch). Each block recomputes
// the small tables into ITS OWN LDS (no k0, no ws dependency, no sync):
//   bpack_s: MFMA1 B-frags (12288 bf16)  — layer-1 weights reformatted
//   b2_s:    MFMA2' B-frags (1536 bf16)  — rs*M^T tiles + rs*r column
//   u_s/wv_s/cc_s: folded bias terms
// Writes out_alpha and ws_ov only (KN finishes out_x next dispatch).
// ---------------------------------------------------------------------------
__global__ __launch_bounds__(256) void ka_kernel(
    const float* __restrict__ obs,
    const float* __restrict__ Wk1, const float* __restrict__ Wq1, const float* __restrict__ Wv1,
    const float* __restrict__ Wk2, const float* __restrict__ bk2,
    const float* __restrict__ Wq2, const float* __restrict__ bq2,
    const float* __restrict__ Wv2, const float* __restrict__ bv2,
    const float* __restrict__ Wval,
    const float* __restrict__ bk1p, const float* __restrict__ bq1p, const float* __restrict__ bv1p,
    float* __restrict__ out_alpha, float* __restrict__ ws_ov)
{
  __shared__ __align__(16) unsigned short bpack_s[12288];
  __shared__ __align__(16) unsigned short b2_s[1536];
  __shared__ __align__(16) float u_s[32], wv_s[32], cc_s[2];
  __shared__ __align__(16) unsigned short hk_s[4][512];
  __shared__ __align__(16) unsigned short hq_s[4][512];
  __shared__ __align__(16) unsigned short tq_s[4][512];
  __shared__ __align__(16) float rql_s[4][16];
  __shared__ __align__(16) float vvl_s[4][16];

  const int t = threadIdx.x;
  const int wid = t >> 6, l = t & 63;
  const int b = blockIdx.x * 4 + wid;
  const int li = l & 15, gp = l >> 4;
  const float rs = 0.08838834764831845f;  // 1/sqrt(128)

  // ---- issue obs loads first (HBM latency hides under table build)
  const float* orow = obs + (size_t)(b * 16 + li) * 128 + gp * 8;
  float4 ob[8];
#pragma unroll
  for (int kc = 0; kc < 4; kc++){
    ob[kc * 2]     = *(const float4*)(orow + kc * 32);
    ob[kc * 2 + 1] = *(const float4*)(orow + kc * 32 + 4);
  }

  // ================= phase 1: in-block table build =========================
  // tile2 zeros (slots with li!=0 only; li==0 slots get the r-column below)
  for (int i = t; i < 512; i += 256)
    if ((i >> 3) & 15) b2_s[1024 + i] = 0;
  // M-table -> b2 tiles 0/1 in frag order
  for (int idx = t; idx < 1024; idx += 256){
    const int h = idx & 31, g = idx >> 5;
    const float val = rs * dot128(Wk2 + h * 128, Wq2 + g * 128);
    b2_s[(h >> 4) * 512 + ((((g >> 3) << 4) | (h & 15)) << 3) + (g & 7)] = f2bf(val);
  }
  // r-column of tile2 (li==0 lanes)
  for (int g = t; g < 32; g += 256){
    const float val = rs * dot128(Wq2 + g * 128, bk2);
    b2_s[1024 + (g >> 3) * 128 + (g & 7)] = f2bf(val);
  }
  // folded bias vectors
  for (int idx = t; idx < 66; idx += 256){
    if (idx < 32)       u_s[idx]       = rs * dot128(Wk2 + idx * 128, bq2);
    else if (idx < 64)  wv_s[idx - 32] = dot128(Wv2 + (idx - 32) * 128, Wval);
    else if (idx == 64) cc_s[0]        = rs * dot128(bk2, bq2);
    else                cc_s[1]        = dot128(bv2, Wval);
  }
  // Bpack reformat (48 elements per thread)
  for (int idx = t; idx < 12288; idx += 256){
    const int e  = idx & 7;
    const int ll = (idx >> 3) & 63;
    const int kc = (idx >> 9) & 3;
    const int nt = (idx >> 11) & 1;
    const int m  = idx >> 12;
    const float* W1 = (m == 0) ? Wk1 : ((m == 1) ? Wq1 : Wv1);
    bpack_s[idx] = f2bf(W1[(kc * 32 + (ll >> 4) * 8 + e) * 32 + nt * 16 + (ll & 15)]);
  }
  __syncthreads();

  // ================= phase 2: attention (r3/r6-validated path) =============
  const bf16x8 b20 = *(const bf16x8*)(b2_s + (size_t)l * 8);
  const bf16x8 b21 = *(const bf16x8*)(b2_s + 512 + (size_t)l * 8);
  const bf16x8 b22 = *(const bf16x8*)(b2_s + 1024 + (size_t)l * 8);
  const float u0 = u_s[li], u1 = u_s[16 + li];
  const float wv0 = wv_s[li], wv1 = wv_s[16 + li];
  const float ccv = cc_s[0], cvv = cc_s[1];
  const float bk0 = bk1p[li], bk1v = bk1p[16 + li];
  const float bq0 = bq1p[li], bq1v = bq1p[16 + li];
  const float bv0 = bv1p[li], bv1v = bv1p[16 + li];

  bf16x8 afr[4];
#pragma unroll
  for (int kc = 0; kc < 4; kc++){
    bf16x8 a;
    a[0]=(short)f2bf(ob[kc*2].x); a[1]=(short)f2bf(ob[kc*2].y);
    a[2]=(short)f2bf(ob[kc*2].z); a[3]=(short)f2bf(ob[kc*2].w);
    a[4]=(short)f2bf(ob[kc*2+1].x); a[5]=(short)f2bf(ob[kc*2+1].y);
    a[6]=(short)f2bf(ob[kc*2+1].z); a[7]=(short)f2bf(ob[kc*2+1].w);
    afr[kc] = a;
  }
  f32x4 acc[6];
#pragma unroll
  for (int mt = 0; mt < 6; mt++){ f32x4 z = {0.f,0.f,0.f,0.f}; acc[mt] = z; }
#pragma unroll
  for (int mt = 0; mt < 6; mt++){
#pragma unroll
    for (int kc = 0; kc < 4; kc++){
      const bf16x8 bfr = *(const bf16x8*)(bpack_s + (size_t)((mt*4+kc)*64 + l) * 8);
      acc[mt] = __builtin_amdgcn_mfma_f32_16x16x32_bf16(afr[kc], bfr, acc[mt], 0, 0, 0);
    }
  }

  unsigned short* hkb = hk_s[wid];
  unsigned short* hqb = hq_s[wid];
#pragma unroll
  for (int tile = 0; tile < 2; tile++){
    const float bk_ = tile ? bk1v : bk0;
    const float bq_ = tile ? bq1v : bq0;
    f32x4 ck = acc[tile], cq = acc[2 + tile];
#pragma unroll
    for (int r = 0; r < 4; r++){
      hkb[(gp*4+r)*32 + tile*16 + li] = f2bf(fast_tanh(ck[r] + bk_));
      hqb[(gp*4+r)*32 + tile*16 + li] = f2bf(fast_tanh(cq[r] + bq_));
    }
  }

  { // vv[j] = wv . tanh(h_v[j]) + cv
    f32x4 c0 = acc[4], c1 = acc[5];
    float vp0 = wv0*fast_tanh(c0[0]+bv0) + wv1*fast_tanh(c1[0]+bv1v);
    float vp1 = wv0*fast_tanh(c0[1]+bv0) + wv1*fast_tanh(c1[1]+bv1v);
    float vp2 = wv0*fast_tanh(c0[2]+bv0) + wv1*fast_tanh(c1[2]+bv1v);
    float vp3 = wv0*fast_tanh(c0[3]+bv0) + wv1*fast_tanh(c1[3]+bv1v);
    GRPSUM(vp0); GRPSUM(vp1); GRPSUM(vp2); GRPSUM(vp3);
    if (li == 0){
      float4 vq; vq.x = vp0+cvv; vq.y = vp1+cvv; vq.z = vp2+cvv; vq.w = vp3+cvv;
      *(float4*)&vvl_s[wid][gp*4] = vq;
    }
  }

  // MFMA2': tq = hq.(rs*M^T) + rs*u ; tile2 -> rs*(rq + cc)
  const bf16x8 aq = *(const bf16x8*)(hqb + li*32 + gp*8);
  f32x4 cu0 = {u0,u0,u0,u0}, cu1 = {u1,u1,u1,u1}, cu2 = {ccv,ccv,ccv,ccv};
  f32x4 tq0 = __builtin_amdgcn_mfma_f32_16x16x32_bf16(aq, b20, cu0, 0, 0, 0);
  f32x4 tq1 = __builtin_amdgcn_mfma_f32_16x16x32_bf16(aq, b21, cu1, 0, 0, 0);
  f32x4 rqt = __builtin_amdgcn_mfma_f32_16x16x32_bf16(aq, b22, cu2, 0, 0, 0);
  if (li == 0){
    float4 rv; rv.x = rqt[0]; rv.y = rqt[1]; rv.z = rqt[2]; rv.w = rqt[3];
    *(float4*)&rql_s[wid][gp*4] = rv;
  }
  unsigned short* tqb = tq_s[wid];
#pragma unroll
  for (int r = 0; r < 4; r++){
    tqb[(gp*4+r)*32 + li]      = f2bf(tq0[r]);
    tqb[(gp*4+r)*32 + 16 + li] = f2bf(tq1[r]);
  }

  // MFMA3: S[j][i] = hk[j] . tq[i]
  const bf16x8 ak = *(const bf16x8*)(hkb + li*32 + gp*8);
  const bf16x8 bt = *(const bf16x8*)(tqb + li*32 + gp*8);
  f32x4 zz = {0.f,0.f,0.f,0.f};
  f32x4 S = __builtin_amdgcn_mfma_f32_16x16x32_bf16(ak, bt, zz, 0, 0, 0);
  const float rc = rql_s[wid][li];
  float s0 = S[0]+rc, s1 = S[1]+rc, s2 = S[2]+rc, s3 = S[3]+rc;

  // softmax over senders j
  float mx = fmaxf(fmaxf(s0, s1), fmaxf(s2, s3));
  mx = fmaxf(mx, __shfl_xor(mx, 16)); mx = fmaxf(mx, __shfl_xor(mx, 32));
  float e0 = __expf(s0-mx), e1 = __expf(s1-mx), e2 = __expf(s2-mx), e3 = __expf(s3-mx);
  float sm = e0+e1+e2+e3;
  sm += __shfl_xor(sm, 16); sm += __shfl_xor(sm, 32);
  const float inv = 1.f / sm;
  const float a0 = e0*inv, a1 = e1*inv, a2 = e2*inv, a3 = e3*inv;

  // alpha out via LDS transpose (tq_s reused as float[256])
  float* aT = (float*)tqb;
  { float4 av4; av4.x = a0; av4.y = a1; av4.z = a2; av4.w = a3;
    *(float4*)&aT[li*16 + gp*4] = av4; }
  { float4 o4 = *(const float4*)&aT[l*4];
    *(float4*)(out_alpha + (size_t)b*256 + l*4) = o4; }

  // ov[i] = sum_j alpha[i][j] * vv[j]  -> ws_ov
  float4 vq4 = *(const float4*)&vvl_s[wid][gp*4];
  float ovp = a0*vq4.x + a1*vq4.y + a2*vq4.z + a3*vq4.w;
  ovp += __shfl_xor(ovp, 16); ovp += __shfl_xor(ovp, 32);
  if (l < 16) ws_ov[(size_t)b*16 + l] = ovp;
}

// ---------------------------------------------------------------------------
// KN: one block = one batch. Noise streaming (all loads up-front) + pv/av +
// final combine (reads ws_ov from the previous dispatch). Single out_x write.
// ---------------------------------------------------------------------------
__global__ __launch_bounds__(256) void kn_kernel(
    const float* __restrict__ policies, const float* __restrict__ actions,
    const float* __restrict__ noise, const float* __restrict__ weights,
    const float* __restrict__ Wval, const float* __restrict__ bval,
    const float* __restrict__ ws_ov, float* __restrict__ out_x)
{
  __shared__ __align__(16) float nvw[256];
  __shared__ __align__(16) float pvl[16], avl[16], ovl[16];

  const int b = blockIdx.x, t = threadIdx.x;
  const int w = t >> 6, l = t & 63;
  const int q8 = l & 7, r8 = l >> 3;
  const float4 wv4 = *(const float4*)(Wval + 128 + q8 * 4);

  // ov + pol/act loads (wave 0), issued before the noise stream
  float4 pA0, pA1, aA0, aA1, wpa, wpb;
  const int jp = l >> 2, seg = l & 3;
  if (w == 0){
    if (t < 16) ovl[t] = ws_ov[(size_t)b * 16 + t];
    const float* pp = policies + (size_t)(b * 16 + jp) * 32 + seg * 8;
    const float* ap = actions  + (size_t)(b * 16 + jp) * 32 + seg * 8;
    pA0 = *(const float4*)(pp);
    pA1 = *(const float4*)(pp + 4);
    aA0 = *(const float4*)(ap);
    aA1 = *(const float4*)(ap + 4);
    wpa = *(const float4*)(Wval + 128 + seg * 8);
    wpb = *(const float4*)(Wval + 132 + seg * 8);
  }

  // 64 rows per wave, 8 up-front float4 loads per lane (1 latency exposure)
  const float* nbl = noise + (size_t)b * 8192 + (w * 64 + r8) * 32 + q8 * 4;
  float4 nz[8];
#pragma unroll
  for (int p = 0; p < 8; p++) nz[p] = *(const float4*)(nbl + p * 256);
#pragma unroll
  for (int p = 0; p < 8; p++){
    float s = nz[p].x*wv4.x + nz[p].y*wv4.y + nz[p].z*wv4.z + nz[p].w*wv4.w;
    s += __shfl_xor(s, 1); s += __shfl_xor(s, 2); s += __shfl_xor(s, 4);
    if (q8 == 0) nvw[w * 64 + p * 8 + r8] = s;
  }

  if (w == 0){
    float pvv = pA0.x*wpa.x + pA0.y*wpa.y + pA0.z*wpa.z + pA0.w*wpa.w
              + pA1.x*wpb.x + pA1.y*wpb.y + pA1.z*wpb.z + pA1.w*wpb.w;
    float avv = aA0.x*wpa.x + aA0.y*wpa.y + aA0.z*wpa.z + aA0.w*wpa.w
              + aA1.x*wpb.x + aA1.y*wpb.y + aA1.z*wpb.z + aA1.w*wpb.w;
    pvv += __shfl_xor(pvv, 1); pvv += __shfl_xor(pvv, 2);
    avv += __shfl_xor(avv, 1); avv += __shfl_xor(avv, 2);
    if (seg == 0){ pvl[jp] = pvv; avl[jp] = avv; }
  }

  __syncthreads();

  // combine, all 256 threads: thread t -> (i = t>>4, j = t&15)
  {
    const float wscal = weights[0];
    const float bvs = bval[0];
    const int j = t & 15;
    const float pv = pvl[j], av = avl[j];
    const float zval = wscal * av + (1.f - wscal) * pv + nvw[t];
    float zs = zval;
    GRPSUM(zs);  // sum over the 16 senders j (lanes sharing i)
    out_x[(size_t)b * 256 + t] = ovl[j] + (pv - zval + zs) * 0.0625f + bvs;
  }
}

// ---------------------------------------------------------------------------
extern "C" void kernel_launch(void* const* d_in, const int* in_sizes, int n_in,
                              void* d_out, int out_size, void* d_ws, size_t ws_size,
                              hipStream_t stream)
{
  const float* obs      = (const float*)d_in[0];
  const float* policies = (const float*)d_in[1];
  const float* actions  = (const float*)d_in[2];
  const float* weights  = (const float*)d_in[3];
  const float* noise    = (const float*)d_in[4];
  const float* Wk1  = (const float*)d_in[5];
  const float* bk1  = (const float*)d_in[6];
  const float* Wk2  = (const float*)d_in[7];
  const float* bk2  = (const float*)d_in[8];
  const float* Wq1  = (const float*)d_in[9];
  const float* bq1  = (const float*)d_in[10];
  const float* Wq2  = (const float*)d_in[11];
  const float* bq2  = (const float*)d_in[12];
  const float* Wv1  = (const float*)d_in[13];
  const float* bv1  = (const float*)d_in[14];
  const float* Wv2  = (const float*)d_in[15];
  const float* bv2  = (const float*)d_in[16];
  const float* Wval = (const float*)d_in[17];
  const float* bval = (const float*)d_in[18];

  float* out = (float*)d_out;
  float* ws  = (float*)d_ws;
  float* ws_ov = ws;

  const int NODES = in_sizes[0] / 128;
  const int B = NODES / 16;

  float* out_x     = out;
  float* out_alpha = out + (size_t)NODES * 16;

  hipLaunchKernelGGL(ka_kernel, dim3(B / 4), dim3(256), 0, stream,
                     obs, Wk1, Wq1, Wv1, Wk2, bk2, Wq2, bq2, Wv2, bv2, Wval,
                     bk1, bq1, bv1, out_alpha, ws_ov);
  hipLaunchKernelGGL(kn_kernel, dim3(B), dim3(256), 0, stream,
                     policies, actions, noise, weights, Wval, bval,
                     ws_ov, out_x);
}

// Round 11
// 30.596 us; speedup vs baseline: 5.7242x; 2.3480x over previous
//
#include <hip/hip_runtime.h>

typedef __attribute__((ext_vector_type(8))) short bf16x8;
typedef __attribute__((ext_vector_type(4))) float f32x4;

__device__ __forceinline__ unsigned short f2bf(float f){
  union { float f; unsigned int u; } v; v.f = f;
  unsigned int u = v.u;
  return (unsigned short)((u + 0x7FFFu + ((u >> 16) & 1u)) >> 16);  // RNE
}

__device__ __forceinline__ float fast_tanh(float x){
  x = fminf(15.f, fmaxf(-15.f, x));
  float e = __expf(2.f * x);
  return (e - 1.f) / (e + 1.f);
}

__device__ __forceinline__ float dot128(const float* __restrict__ a,
                                        const float* __restrict__ b){
  float s = 0.f;
  for (int c = 0; c < 128; c += 4){
    float4 x = *(const float4*)(a + c);
    float4 y = *(const float4*)(b + c);
    s += x.x*y.x + x.y*y.y + x.z*y.z + x.w*y.w;
  }
  return s;
}

#define GRPSUM(x) { x += __shfl_xor(x, 1); x += __shfl_xor(x, 2); \
                    x += __shfl_xor(x, 4); x += __shfl_xor(x, 8); }

// ws float layout:
//   f[0 .. 6144)    : Bpack  — MFMA1 B-frags (12288 bf16), layer-1 weights
//   f[6144 .. 6912) : B2pack — MFMA2' B-frags (1536 bf16): 3 tiles
//   f[6912 .. 6944) : u'[h]   f[6944..6976): wv[h]
//   f[6976] = rs*(bk2.bq2)    f[6977] = bv2.Wval[0:128]
//   f[7168 .. )     : ws_ov[B*16]

// ---------------------------------------------------------------------------
// k0: precompute tables (validated r3/r4 version, unchanged)
// ---------------------------------------------------------------------------
__global__ __launch_bounds__(64) void k0_kernel(
    const float* __restrict__ Wk1, const float* __restrict__ Wq1, const float* __restrict__ Wv1,
    const float* __restrict__ Wk2, const float* __restrict__ bk2,
    const float* __restrict__ Wq2, const float* __restrict__ bq2,
    const float* __restrict__ Wv2, const float* __restrict__ bv2,
    const float* __restrict__ Wval, float* __restrict__ ws)
{
  const int tid = blockIdx.x * 64 + threadIdx.x;  // 0..4095
  const float rs = 0.08838834764831845f;          // 1/sqrt(128)
  unsigned short* bp = (unsigned short*)ws;
  unsigned short* b2 = (unsigned short*)(ws + 6144);

  if (tid < 1536){
    const int e = tid & 7, l = (tid >> 3) & 63, tt = tid >> 9;
    const int g = (l >> 4) * 8 + e;
    float val = 0.f;
    if (tt < 2){
      const int h = (l & 15) + tt * 16;
      val = rs * dot128(Wk2 + h * 128, Wq2 + g * 128);
    } else if ((l & 15) == 0){
      val = rs * dot128(Wq2 + g * 128, bk2);
    }
    b2[tid] = f2bf(val);
  } else if (tid < 1600){
    const int h = tid - 1536;
    if (h < 32) ws[6912 + h] = rs * dot128(Wk2 + h * 128, bq2);
    else        ws[6944 + (h - 32)] = dot128(Wv2 + (h - 32) * 128, Wval);
  } else if (tid == 1600){
    ws[6976] = rs * dot128(bk2, bq2);
  } else if (tid == 1601){
    ws[6977] = dot128(bv2, Wval);
  }

  for (int idx = tid; idx < 12288; idx += 4096){
    const int e  = idx & 7;
    const int l  = (idx >> 3) & 63;
    const int kc = (idx >> 9) & 3;
    const int nt = (idx >> 11) & 1;
    const int m  = idx >> 12;
    const float* W1 = (m == 0) ? Wk1 : ((m == 1) ? Wq1 : Wv1);
    const int krow = kc * 32 + (l >> 4) * 8 + e;
    const int col  = nt * 16 + (l & 15);
    bp[idx] = f2bf(W1[krow * 32 + col]);
  }
}

// ---------------------------------------------------------------------------
// K1: mixed, no inter-block dependency.
//   blocks [0, BA)     : attention (wave per batch) -> alpha + ws_ov
//   blocks [BA, BA+B)  : noise + pv/av + partial combine (no ov) -> out_x
// Attention first in the grid so its latency chains co-schedule with the
// noise blocks' BW streaming on every CU.
// ---------------------------------------------------------------------------
__global__ __launch_bounds__(256) void k1_kernel(
    const float* __restrict__ obs,
    const float* __restrict__ policies, const float* __restrict__ actions,
    const float* __restrict__ noise, const float* __restrict__ weights,
    const float* __restrict__ bk1p, const float* __restrict__ bq1p, const float* __restrict__ bv1p,
    const float* __restrict__ Wval, const float* __restrict__ bval,
    const float* __restrict__ ws,
    float* __restrict__ out_x, float* __restrict__ out_alpha,
    float* __restrict__ ws_ov, int BA)
{
  const int t = threadIdx.x;

  if ((int)blockIdx.x < BA){
    // ===================== attention (validated r3 path) ====================
    __shared__ __align__(16) unsigned short hk_s[4][512];
    __shared__ __align__(16) unsigned short hq_s[4][512];
    __shared__ __align__(16) unsigned short tq_s[4][512];
    __shared__ __align__(16) float rql_s[4][16];
    __shared__ __align__(16) float vvl_s[4][16];

    const int wid = t >> 6, l = t & 63;
    const int b = blockIdx.x * 4 + wid;
    const int li = l & 15, gp = l >> 4;

    const float* orow = obs + (size_t)(b * 16 + li) * 128 + gp * 8;
    float4 ob[8];
#pragma unroll
    for (int kc = 0; kc < 4; kc++){
      ob[kc * 2]     = *(const float4*)(orow + kc * 32);
      ob[kc * 2 + 1] = *(const float4*)(orow + kc * 32 + 4);
    }

    const bf16x8* bp  = (const bf16x8*)ws;
    const bf16x8* b2p = (const bf16x8*)(ws + 6144);
    const bf16x8 b20 = b2p[l], b21 = b2p[64 + l], b22 = b2p[128 + l];
    const float u0 = ws[6912 + li], u1 = ws[6928 + li];
    const float wv0 = ws[6944 + li], wv1 = ws[6960 + li];
    const float ccv = ws[6976], cvv = ws[6977];
    const float bk0 = bk1p[li], bk1v = bk1p[16 + li];
    const float bq0 = bq1p[li], bq1v = bq1p[16 + li];
    const float bv0 = bv1p[li], bv1v = bv1p[16 + li];

    bf16x8 afr[4];
#pragma unroll
    for (int kc = 0; kc < 4; kc++){
      bf16x8 a;
      a[0]=(short)f2bf(ob[kc*2].x); a[1]=(short)f2bf(ob[kc*2].y);
      a[2]=(short)f2bf(ob[kc*2].z); a[3]=(short)f2bf(ob[kc*2].w);
      a[4]=(short)f2bf(ob[kc*2+1].x); a[5]=(short)f2bf(ob[kc*2+1].y);
      a[6]=(short)f2bf(ob[kc*2+1].z); a[7]=(short)f2bf(ob[kc*2+1].w);
      afr[kc] = a;
    }
    f32x4 acc[6];
#pragma unroll
    for (int mt = 0; mt < 6; mt++){ f32x4 z = {0.f,0.f,0.f,0.f}; acc[mt] = z; }
#pragma unroll
    for (int mt = 0; mt < 6; mt++){
#pragma unroll
      for (int kc = 0; kc < 4; kc++)
        acc[mt] = __builtin_amdgcn_mfma_f32_16x16x32_bf16(afr[kc], bp[(mt*4+kc)*64 + l], acc[mt], 0, 0, 0);
    }

    unsigned short* hkb = hk_s[wid];
    unsigned short* hqb = hq_s[wid];
#pragma unroll
    for (int tile = 0; tile < 2; tile++){
      const float bk_ = tile ? bk1v : bk0;
      const float bq_ = tile ? bq1v : bq0;
      f32x4 ck = acc[tile], cq = acc[2 + tile];
#pragma unroll
      for (int r = 0; r < 4; r++){
        hkb[(gp*4+r)*32 + tile*16 + li] = f2bf(fast_tanh(ck[r] + bk_));
        hqb[(gp*4+r)*32 + tile*16 + li] = f2bf(fast_tanh(cq[r] + bq_));
      }
    }

    { // vv[j] = wv . tanh(h_v[j]) + cv
      f32x4 c0 = acc[4], c1 = acc[5];
      float vp0 = wv0*fast_tanh(c0[0]+bv0) + wv1*fast_tanh(c1[0]+bv1v);
      float vp1 = wv0*fast_tanh(c0[1]+bv0) + wv1*fast_tanh(c1[1]+bv1v);
      float vp2 = wv0*fast_tanh(c0[2]+bv0) + wv1*fast_tanh(c1[2]+bv1v);
      float vp3 = wv0*fast_tanh(c0[3]+bv0) + wv1*fast_tanh(c1[3]+bv1v);
      GRPSUM(vp0); GRPSUM(vp1); GRPSUM(vp2); GRPSUM(vp3);
      if (li == 0){
        float4 vq; vq.x = vp0+cvv; vq.y = vp1+cvv; vq.z = vp2+cvv; vq.w = vp3+cvv;
        *(float4*)&vvl_s[wid][gp*4] = vq;
      }
    }

    // MFMA2': tq = hq.(rs*M^T) + rs*u ; tile2 -> rs*(rq + cc)
    const bf16x8 aq = *(const bf16x8*)(hqb + li*32 + gp*8);
    f32x4 cu0 = {u0,u0,u0,u0}, cu1 = {u1,u1,u1,u1}, cu2 = {ccv,ccv,ccv,ccv};
    f32x4 tq0 = __builtin_amdgcn_mfma_f32_16x16x32_bf16(aq, b20, cu0, 0, 0, 0);
    f32x4 tq1 = __builtin_amdgcn_mfma_f32_16x16x32_bf16(aq, b21, cu1, 0, 0, 0);
    f32x4 rqt = __builtin_amdgcn_mfma_f32_16x16x32_bf16(aq, b22, cu2, 0, 0, 0);
    if (li == 0){
      float4 rv; rv.x = rqt[0]; rv.y = rqt[1]; rv.z = rqt[2]; rv.w = rqt[3];
      *(float4*)&rql_s[wid][gp*4] = rv;
    }
    unsigned short* tqb = tq_s[wid];
#pragma unroll
    for (int r = 0; r < 4; r++){
      tqb[(gp*4+r)*32 + li]      = f2bf(tq0[r]);
      tqb[(gp*4+r)*32 + 16 + li] = f2bf(tq1[r]);
    }

    // MFMA3: S[j][i] = hk[j] . tq[i]
    const bf16x8 ak = *(const bf16x8*)(hkb + li*32 + gp*8);
    const bf16x8 bt = *(const bf16x8*)(tqb + li*32 + gp*8);
    f32x4 zz = {0.f,0.f,0.f,0.f};
    f32x4 S = __builtin_amdgcn_mfma_f32_16x16x32_bf16(ak, bt, zz, 0, 0, 0);
    const float rc = rql_s[wid][li];
    float s0 = S[0]+rc, s1 = S[1]+rc, s2 = S[2]+rc, s3 = S[3]+rc;

    // softmax over senders j
    float mx = fmaxf(fmaxf(s0, s1), fmaxf(s2, s3));
    mx = fmaxf(mx, __shfl_xor(mx, 16)); mx = fmaxf(mx, __shfl_xor(mx, 32));
    float e0 = __expf(s0-mx), e1 = __expf(s1-mx), e2 = __expf(s2-mx), e3 = __expf(s3-mx);
    float sm = e0+e1+e2+e3;
    sm += __shfl_xor(sm, 16); sm += __shfl_xor(sm, 32);
    const float inv = 1.f / sm;
    const float a0 = e0*inv, a1 = e1*inv, a2 = e2*inv, a3 = e3*inv;

    // alpha out via LDS transpose (tq_s reused as float[256])
    float* aT = (float*)tqb;
    { float4 av4; av4.x = a0; av4.y = a1; av4.z = a2; av4.w = a3;
      *(float4*)&aT[li*16 + gp*4] = av4; }
    { float4 o4 = *(const float4*)&aT[l*4];
      *(float4*)(out_alpha + (size_t)b*256 + l*4) = o4; }

    // ov[i] = sum_j alpha[i][j] * vv[j]
    float4 vq4 = *(const float4*)&vvl_s[wid][gp*4];
    float ovp = a0*vq4.x + a1*vq4.y + a2*vq4.z + a3*vq4.w;
    ovp += __shfl_xor(ovp, 16); ovp += __shfl_xor(ovp, 32);
    if (l < 16) ws_ov[(size_t)b*16 + l] = ovp;
    return;
  }

  // ===================== noise (validated r6 path, partial combine) ========
  {
    __shared__ __align__(16) float nvw[256];
    __shared__ __align__(16) float pvl[16], avl[16];

    const int b = blockIdx.x - BA;
    const int w = t >> 6, l = t & 63;
    const int q8 = l & 7, r8 = l >> 3;
    const float4 wv4 = *(const float4*)(Wval + 128 + q8 * 4);

    float4 pA0, pA1, aA0, aA1, wpa, wpb;
    const int jp = l >> 2, seg = l & 3;
    if (w == 0){
      const float* pp = policies + (size_t)(b * 16 + jp) * 32 + seg * 8;
      const float* ap = actions  + (size_t)(b * 16 + jp) * 32 + seg * 8;
      pA0 = *(const float4*)(pp);
      pA1 = *(const float4*)(pp + 4);
      aA0 = *(const float4*)(ap);
      aA1 = *(const float4*)(ap + 4);
      wpa = *(const float4*)(Wval + 128 + seg * 8);
      wpb = *(const float4*)(Wval + 132 + seg * 8);
    }

    // 64 rows per wave, 8 up-front float4 loads per lane (1 latency exposure)
    const float* nbl = noise + (size_t)b * 8192 + (w * 64 + r8) * 32 + q8 * 4;
    float4 nz[8];
#pragma unroll
    for (int p = 0; p < 8; p++) nz[p] = *(const float4*)(nbl + p * 256);
#pragma unroll
    for (int p = 0; p < 8; p++){
      float s = nz[p].x*wv4.x + nz[p].y*wv4.y + nz[p].z*wv4.z + nz[p].w*wv4.w;
      s += __shfl_xor(s, 1); s += __shfl_xor(s, 2); s += __shfl_xor(s, 4);
      if (q8 == 0) nvw[w * 64 + p * 8 + r8] = s;
    }

    if (w == 0){
      float pvv = pA0.x*wpa.x + pA0.y*wpa.y + pA0.z*wpa.z + pA0.w*wpa.w
                + pA1.x*wpb.x + pA1.y*wpb.y + pA1.z*wpb.z + pA1.w*wpb.w;
      float avv = aA0.x*wpa.x + aA0.y*wpa.y + aA0.z*wpa.z + aA0.w*wpa.w
                + aA1.x*wpb.x + aA1.y*wpb.y + aA1.z*wpb.z + aA1.w*wpb.w;
      pvv += __shfl_xor(pvv, 1); pvv += __shfl_xor(pvv, 2);
      avv += __shfl_xor(avv, 1); avv += __shfl_xor(avv, 2);
      if (seg == 0){ pvl[jp] = pvv; avl[jp] = avv; }
    }

    __syncthreads();

    if (w == 0){
      // partial combine (no ov): lane l -> out[i = l>>2][j = (l&3)*4 + 0..3]
      const float wscal = weights[0];
      const float bvs = bval[0];
      const int i = l >> 2, j0 = (l & 3) * 4;
      float4 pv4 = *(const float4*)&pvl[j0];
      float4 av4 = *(const float4*)&avl[j0];
      float4 nv4 = *(const float4*)&nvw[i * 16 + j0];
      const float om = 1.f - wscal;
      float z0 = wscal * av4.x + om * pv4.x + nv4.x;
      float z1 = wscal * av4.y + om * pv4.y + nv4.y;
      float z2 = wscal * av4.z + om * pv4.z + nv4.z;
      float z3 = wscal * av4.w + om * pv4.w + nv4.w;
      float zs = z0 + z1 + z2 + z3;
      zs += __shfl_xor(zs, 1); zs += __shfl_xor(zs, 2);  // over 16 senders j
      float4 o;
      o.x = (pv4.x - z0 + zs) * 0.0625f + bvs;
      o.y = (pv4.y - z1 + zs) * 0.0625f + bvs;
      o.z = (pv4.z - z2 + zs) * 0.0625f + bvs;
      o.w = (pv4.w - z3 + zs) * 0.0625f + bvs;
      *(float4*)(out_x + (size_t)b * 256 + l * 4) = o;   // NO ov yet
    }
  }
}

// ---------------------------------------------------------------------------
// K2: out_x += ov[j] broadcast.  512 blocks x 256 threads x float4.
// ---------------------------------------------------------------------------
__global__ __launch_bounds__(256) void k2_kernel(
    const float* __restrict__ ws_ov, float* __restrict__ out_x)
{
  const int f4 = blockIdx.x * 256 + threadIdx.x;   // float4 index
  const int b = f4 >> 6;                           // 64 float4 per batch
  const int q = f4 & 63;
  const int j0 = (q & 3) * 4;
  float4 ov4 = *(const float4*)(ws_ov + (size_t)b * 16 + j0);
  float4 x4  = *(const float4*)(out_x + (size_t)f4 * 4);
  x4.x += ov4.x; x4.y += ov4.y; x4.z += ov4.z; x4.w += ov4.w;
  *(float4*)(out_x + (size_t)f4 * 4) = x4;
}

// ---------------------------------------------------------------------------
extern "C" void kernel_launch(void* const* d_in, const int* in_sizes, int n_in,
                              void* d_out, int out_size, void* d_ws, size_t ws_size,
                              hipStream_t stream)
{
  const float* obs      = (const float*)d_in[0];
  const float* policies = (const float*)d_in[1];
  const float* actions  = (const float*)d_in[2];
  const float* weights  = (const float*)d_in[3];
  const float* noise    = (const float*)d_in[4];
  const float* Wk1  = (const float*)d_in[5];
  const float* bk1  = (const float*)d_in[6];
  const float* Wk2  = (const float*)d_in[7];
  const float* bk2  = (const float*)d_in[8];
  const float* Wq1  = (const float*)d_in[9];
  const float* bq1  = (const float*)d_in[10];
  const float* Wq2  = (const float*)d_in[11];
  const float* bq2  = (const float*)d_in[12];
  const float* Wv1  = (const float*)d_in[13];
  const float* bv1  = (const float*)d_in[14];
  const float* Wv2  = (const float*)d_in[15];
  const float* bv2  = (const float*)d_in[16];
  const float* Wval = (const float*)d_in[17];
  const float* bval = (const float*)d_in[18];

  float* out = (float*)d_out;
  float* ws  = (float*)d_ws;
  float* ws_ov = ws + 7168;

  const int NODES = in_sizes[0] / 128;
  const int B = NODES / 16;
  const int BA = B / 4;

  float* out_x     = out;
  float* out_alpha = out + (size_t)NODES * 16;

  hipLaunchKernelGGL(k0_kernel, dim3(64), dim3(64), 0, stream,
                     Wk1, Wq1, Wv1, Wk2, bk2, Wq2, bq2, Wv2, bv2, Wval, ws);
  hipLaunchKernelGGL(k1_kernel, dim3(BA + B), dim3(256), 0, stream,
                     obs, policies, actions, noise, weights,
                     bk1, bq1, bv1, Wval, bval, ws,
                     out_x, out_alpha, ws_ov, BA);
  hipLaunchKernelGGL(k2_kernel, dim3((NODES * 16) / 1024), dim3(256), 0, stream,
                     ws_ov, out_x);
}

// Round 12
// 29.690 us; speedup vs baseline: 5.8989x; 1.0305x over previous
//
#include <hip/hip_runtime.h>

typedef __attribute__((ext_vector_type(8))) short bf16x8;
typedef __attribute__((ext_vector_type(4))) float f32x4;

__device__ __forceinline__ unsigned short f2bf(float f){
  union { float f; unsigned int u; } v; v.f = f;
  unsigned int u = v.u;
  return (unsigned short)((u + 0x7FFFu + ((u >> 16) & 1u)) >> 16);  // RNE
}

__device__ __forceinline__ float fast_tanh(float x){
  x = fminf(15.f, fmaxf(-15.f, x));
  float e = __expf(2.f * x);
  return (e - 1.f) / (e + 1.f);
}

__device__ __forceinline__ float dot128(const float* __restrict__ a,
                                        const float* __restrict__ b){
  float s = 0.f;
  for (int c = 0; c < 128; c += 4){
    float4 x = *(const float4*)(a + c);
    float4 y = *(const float4*)(b + c);
    s += x.x*y.x + x.y*y.y + x.z*y.z + x.w*y.w;
  }
  return s;
}

#define GRPSUM(x) { x += __shfl_xor(x, 1); x += __shfl_xor(x, 2); \
                    x += __shfl_xor(x, 4); x += __shfl_xor(x, 8); }

// ws float layout:
//   f[0 .. 6144)    : Bpack  — MFMA1 B-frags (12288 bf16), layer-1 weights
//   f[6144 .. 6912) : B2pack — MFMA2' B-frags (1536 bf16): 3 tiles
//   f[6912 .. 6944) : u'[h]   f[6944..6976): wv[h]
//   f[6976] = rs*(bk2.bq2)    f[6977] = bv2.Wval[0:128]

// ---------------------------------------------------------------------------
// KN: blocks 0..3 compute tables (k0 work); blocks 4..B+3: noise streaming +
// pv/av + PRD combine (WITHOUT ov term) -> out_x partial.  (r6, unchanged)
// ---------------------------------------------------------------------------
__global__ __launch_bounds__(256) void kn_kernel(
    const float* __restrict__ policies, const float* __restrict__ actions,
    const float* __restrict__ noise, const float* __restrict__ weights,
    const float* __restrict__ Wval, const float* __restrict__ bval,
    const float* __restrict__ Wk1, const float* __restrict__ Wq1, const float* __restrict__ Wv1,
    const float* __restrict__ Wk2, const float* __restrict__ bk2,
    const float* __restrict__ Wq2, const float* __restrict__ bq2,
    const float* __restrict__ Wv2, const float* __restrict__ bv2,
    float* __restrict__ ws, float* __restrict__ out_x)
{
  const int t = threadIdx.x;

  if ((int)blockIdx.x < 4){
    const int tid2 = blockIdx.x * 256 + t;   // 0..1023
    const float rs = 0.08838834764831845f;   // 1/sqrt(128)
    unsigned short* bp = (unsigned short*)ws;
    unsigned short* b2 = (unsigned short*)(ws + 6144);

    for (int d = tid2; d < 1602; d += 1024){
      if (d < 1536){
        const int e = d & 7, l = (d >> 3) & 63, tt = d >> 9;
        const int g = (l >> 4) * 8 + e;
        float val = 0.f;
        if (tt < 2){
          const int h = (l & 15) + tt * 16;
          val = rs * dot128(Wk2 + h * 128, Wq2 + g * 128);
        } else if ((l & 15) == 0){
          val = rs * dot128(Wq2 + g * 128, bk2);
        }
        b2[d] = f2bf(val);
      } else if (d < 1600){
        const int h = d - 1536;
        if (h < 32) ws[6912 + h] = rs * dot128(Wk2 + h * 128, bq2);
        else        ws[6944 + (h - 32)] = dot128(Wv2 + (h - 32) * 128, Wval);
      } else if (d == 1600){
        ws[6976] = rs * dot128(bk2, bq2);
      } else { // d == 1601
        ws[6977] = dot128(bv2, Wval);
      }
    }
    for (int idx = tid2; idx < 12288; idx += 1024){
      const int e  = idx & 7;
      const int l  = (idx >> 3) & 63;
      const int kc = (idx >> 9) & 3;
      const int nt = (idx >> 11) & 1;
      const int m  = idx >> 12;
      const float* W1 = (m == 0) ? Wk1 : ((m == 1) ? Wq1 : Wv1);
      const int krow = kc * 32 + (l >> 4) * 8 + e;
      const int col  = nt * 16 + (l & 15);
      bp[idx] = f2bf(W1[krow * 32 + col]);
    }
    return;
  }

  __shared__ __align__(16) float nvw[256];
  __shared__ __align__(16) float pvl[16], avl[16];

  const int b = blockIdx.x - 4;
  const int w = t >> 6, l = t & 63;
  const int q8 = l & 7, r8 = l >> 3;
  const float4 wv4 = *(const float4*)(Wval + 128 + q8 * 4);

  float4 pA0, pA1, aA0, aA1, wpa, wpb;
  const int jp = l >> 2, seg = l & 3;
  if (w == 0){
    const float* pp = policies + (size_t)(b * 16 + jp) * 32 + seg * 8;
    const float* ap = actions  + (size_t)(b * 16 + jp) * 32 + seg * 8;
    pA0 = *(const float4*)(pp);
    pA1 = *(const float4*)(pp + 4);
    aA0 = *(const float4*)(ap);
    aA1 = *(const float4*)(ap + 4);
    wpa = *(const float4*)(Wval + 128 + seg * 8);
    wpb = *(const float4*)(Wval + 132 + seg * 8);
  }

  const float* nbl = noise + (size_t)b * 8192 + (w * 64 + r8) * 32 + q8 * 4;
  float4 nz[8];
#pragma unroll
  for (int p = 0; p < 8; p++) nz[p] = *(const float4*)(nbl + p * 256);
#pragma unroll
  for (int p = 0; p < 8; p++){
    float s = nz[p].x*wv4.x + nz[p].y*wv4.y + nz[p].z*wv4.z + nz[p].w*wv4.w;
    s += __shfl_xor(s, 1); s += __shfl_xor(s, 2); s += __shfl_xor(s, 4);
    if (q8 == 0) nvw[w * 64 + p * 8 + r8] = s;
  }

  if (w == 0){
    float pvv = pA0.x*wpa.x + pA0.y*wpa.y + pA0.z*wpa.z + pA0.w*wpa.w
              + pA1.x*wpb.x + pA1.y*wpb.y + pA1.z*wpb.z + pA1.w*wpb.w;
    float avv = aA0.x*wpa.x + aA0.y*wpa.y + aA0.z*wpa.z + aA0.w*wpa.w
              + aA1.x*wpb.x + aA1.y*wpb.y + aA1.z*wpb.z + aA1.w*wpb.w;
    pvv += __shfl_xor(pvv, 1); pvv += __shfl_xor(pvv, 2);
    avv += __shfl_xor(avv, 1); avv += __shfl_xor(avv, 2);
    if (seg == 0){ pvl[jp] = pvv; avl[jp] = avv; }
  }

  __syncthreads();

  if (w == 0){
    const float wscal = weights[0];
    const float bvs = bval[0];
    const int i = l >> 2, j0 = (l & 3) * 4;
    float4 pv4 = *(const float4*)&pvl[j0];
    float4 av4 = *(const float4*)&avl[j0];
    float4 nv4 = *(const float4*)&nvw[i * 16 + j0];
    const float om = 1.f - wscal;
    float z0 = wscal * av4.x + om * pv4.x + nv4.x;
    float z1 = wscal * av4.y + om * pv4.y + nv4.y;
    float z2 = wscal * av4.z + om * pv4.z + nv4.z;
    float z3 = wscal * av4.w + om * pv4.w + nv4.w;
    float zs = z0 + z1 + z2 + z3;
    zs += __shfl_xor(zs, 1); zs += __shfl_xor(zs, 2);
    float4 o;
    o.x = (pv4.x - z0 + zs) * 0.0625f + bvs;
    o.y = (pv4.y - z1 + zs) * 0.0625f + bvs;
    o.z = (pv4.z - z2 + zs) * 0.0625f + bvs;
    o.w = (pv4.w - z3 + zs) * 0.0625f + bvs;
    *(float4*)(out_x + (size_t)b * 256 + l * 4) = o;   // NO ov yet
  }
}

// ---------------------------------------------------------------------------
// KA: attention with LDS-staged tables. One coalesced 27KB copy per block,
// then all MFMA B-operands come from LDS with per-mt register double-buffer.
// Epilogue: out_x += ov[j] (RMW of KN partial). Numerics identical to r6.
// ---------------------------------------------------------------------------
__global__ __launch_bounds__(256) void ka_kernel(
    const float* __restrict__ obs,
    const float* __restrict__ bk1p, const float* __restrict__ bq1p, const float* __restrict__ bv1p,
    const float* __restrict__ ws,
    float* __restrict__ out_x, float* __restrict__ out_alpha)
{
  __shared__ __align__(16) unsigned short tabu[13824];  // Bpack(12288) + B2(1536)
  __shared__ __align__(16) float tabf[68];              // u(32) wv(32) cc(2)
  __shared__ __align__(16) unsigned short hk_s[4][512];
  __shared__ __align__(16) unsigned short hq_s[4][512];
  __shared__ __align__(16) unsigned short tq_s[4][512];
  __shared__ __align__(16) float rql_s[4][16];
  __shared__ __align__(16) float vvl_s[4][16];
  __shared__ __align__(16) float ovl_s[4][16];

  const int t = threadIdx.x;
  const int wid = t >> 6, l = t & 63;
  const int b = blockIdx.x * 4 + wid;
  const int li = l & 15, gp = l >> 4;

  // issue obs loads + out_x partial first (HBM latency hides under table copy)
  const float* orow = obs + (size_t)(b * 16 + li) * 128 + gp * 8;
  float4 ob[8];
#pragma unroll
  for (int kc = 0; kc < 4; kc++){
    ob[kc * 2]     = *(const float4*)(orow + kc * 32);
    ob[kc * 2 + 1] = *(const float4*)(orow + kc * 32 + 4);
  }
  float4 x4 = *(const float4*)(out_x + (size_t)b * 256 + l * 4);

  // ---- coalesced table copy ws[0..6912) -> LDS (1728 float4)
  {
    const float4* src = (const float4*)ws;
    float4* dst = (float4*)tabu;
#pragma unroll
    for (int i = 0; i < 7; i++){
      const int idx = t + i * 256;
      if (idx < 1728) dst[idx] = src[idx];
    }
    if (t < 66) tabf[t] = ws[6912 + t];
  }
  __syncthreads();

  const bf16x8* bpl = (const bf16x8*)tabu;            // MFMA1 B-frags (LDS)
  const bf16x8* b2p = (const bf16x8*)(tabu + 12288);  // MFMA2' frags  (LDS)
  const bf16x8 b20 = b2p[l], b21 = b2p[64 + l], b22 = b2p[128 + l];
  const float u0 = tabf[li], u1 = tabf[16 + li];
  const float wv0 = tabf[32 + li], wv1 = tabf[48 + li];
  const float ccv = tabf[64], cvv = tabf[65];
  const float bk0 = bk1p[li], bk1v = bk1p[16 + li];
  const float bq0 = bq1p[li], bq1v = bq1p[16 + li];
  const float bv0 = bv1p[li], bv1v = bv1p[16 + li];

  bf16x8 afr[4];
#pragma unroll
  for (int kc = 0; kc < 4; kc++){
    bf16x8 a;
    a[0]=(short)f2bf(ob[kc*2].x); a[1]=(short)f2bf(ob[kc*2].y);
    a[2]=(short)f2bf(ob[kc*2].z); a[3]=(short)f2bf(ob[kc*2].w);
    a[4]=(short)f2bf(ob[kc*2+1].x); a[5]=(short)f2bf(ob[kc*2+1].y);
    a[6]=(short)f2bf(ob[kc*2+1].z); a[7]=(short)f2bf(ob[kc*2+1].w);
    afr[kc] = a;
  }

  // MFMA1 with double-buffered LDS B-frags
  f32x4 acc[6];
#pragma unroll
  for (int mt = 0; mt < 6; mt++){ f32x4 z = {0.f,0.f,0.f,0.f}; acc[mt] = z; }
  bf16x8 cur0 = bpl[l], cur1 = bpl[64 + l], cur2 = bpl[128 + l], cur3 = bpl[192 + l];
#pragma unroll
  for (int mt = 0; mt < 6; mt++){
    bf16x8 nxt0, nxt1, nxt2, nxt3;
    if (mt < 5){
      const int base = (mt + 1) * 256 + l;
      nxt0 = bpl[base]; nxt1 = bpl[base + 64]; nxt2 = bpl[base + 128]; nxt3 = bpl[base + 192];
    }
    acc[mt] = __builtin_amdgcn_mfma_f32_16x16x32_bf16(afr[0], cur0, acc[mt], 0, 0, 0);
    acc[mt] = __builtin_amdgcn_mfma_f32_16x16x32_bf16(afr[1], cur1, acc[mt], 0, 0, 0);
    acc[mt] = __builtin_amdgcn_mfma_f32_16x16x32_bf16(afr[2], cur2, acc[mt], 0, 0, 0);
    acc[mt] = __builtin_amdgcn_mfma_f32_16x16x32_bf16(afr[3], cur3, acc[mt], 0, 0, 0);
    if (mt < 5){ cur0 = nxt0; cur1 = nxt1; cur2 = nxt2; cur3 = nxt3; }
  }

  unsigned short* hkb = hk_s[wid];
  unsigned short* hqb = hq_s[wid];
#pragma unroll
  for (int tile = 0; tile < 2; tile++){
    const float bk_ = tile ? bk1v : bk0;
    const float bq_ = tile ? bq1v : bq0;
    f32x4 ck = acc[tile], cq = acc[2 + tile];
#pragma unroll
    for (int r = 0; r < 4; r++){
      hkb[(gp*4+r)*32 + tile*16 + li] = f2bf(fast_tanh(ck[r] + bk_));
      hqb[(gp*4+r)*32 + tile*16 + li] = f2bf(fast_tanh(cq[r] + bq_));
    }
  }

  { // vv[j] = wv . tanh(h_v[j]) + cv
    f32x4 c0 = acc[4], c1 = acc[5];
    float vp0 = wv0*fast_tanh(c0[0]+bv0) + wv1*fast_tanh(c1[0]+bv1v);
    float vp1 = wv0*fast_tanh(c0[1]+bv0) + wv1*fast_tanh(c1[1]+bv1v);
    float vp2 = wv0*fast_tanh(c0[2]+bv0) + wv1*fast_tanh(c1[2]+bv1v);
    float vp3 = wv0*fast_tanh(c0[3]+bv0) + wv1*fast_tanh(c1[3]+bv1v);
    GRPSUM(vp0); GRPSUM(vp1); GRPSUM(vp2); GRPSUM(vp3);
    if (li == 0){
      float4 vq; vq.x = vp0+cvv; vq.y = vp1+cvv; vq.z = vp2+cvv; vq.w = vp3+cvv;
      *(float4*)&vvl_s[wid][gp*4] = vq;
    }
  }

  // MFMA2': tq = hq.(rs*M^T) + rs*u ; tile2 -> rs*(rq + cc)
  const bf16x8 aq = *(const bf16x8*)(hqb + li*32 + gp*8);
  f32x4 cu0 = {u0,u0,u0,u0}, cu1 = {u1,u1,u1,u1}, cu2 = {ccv,ccv,ccv,ccv};
  f32x4 tq0 = __builtin_amdgcn_mfma_f32_16x16x32_bf16(aq, b20, cu0, 0, 0, 0);
  f32x4 tq1 = __builtin_amdgcn_mfma_f32_16x16x32_bf16(aq, b21, cu1, 0, 0, 0);
  f32x4 rqt = __builtin_amdgcn_mfma_f32_16x16x32_bf16(aq, b22, cu2, 0, 0, 0);
  if (li == 0){
    float4 rv; rv.x = rqt[0]; rv.y = rqt[1]; rv.z = rqt[2]; rv.w = rqt[3];
    *(float4*)&rql_s[wid][gp*4] = rv;
  }
  unsigned short* tqb = tq_s[wid];
#pragma unroll
  for (int r = 0; r < 4; r++){
    tqb[(gp*4+r)*32 + li]      = f2bf(tq0[r]);
    tqb[(gp*4+r)*32 + 16 + li] = f2bf(tq1[r]);
  }

  // MFMA3: S[j][i] = hk[j] . tq[i]
  const bf16x8 ak = *(const bf16x8*)(hkb + li*32 + gp*8);
  const bf16x8 bt = *(const bf16x8*)(tqb + li*32 + gp*8);
  f32x4 zz = {0.f,0.f,0.f,0.f};
  f32x4 S = __builtin_amdgcn_mfma_f32_16x16x32_bf16(ak, bt, zz, 0, 0, 0);
  const float rc = rql_s[wid][li];
  float s0 = S[0]+rc, s1 = S[1]+rc, s2 = S[2]+rc, s3 = S[3]+rc;

  // softmax over senders j
  float mx = fmaxf(fmaxf(s0, s1), fmaxf(s2, s3));
  mx = fmaxf(mx, __shfl_xor(mx, 16)); mx = fmaxf(mx, __shfl_xor(mx, 32));
  float e0 = __expf(s0-mx), e1 = __expf(s1-mx), e2 = __expf(s2-mx), e3 = __expf(s3-mx);
  float sm = e0+e1+e2+e3;
  sm += __shfl_xor(sm, 16); sm += __shfl_xor(sm, 32);
  const float inv = 1.f / sm;
  const float a0 = e0*inv, a1 = e1*inv, a2 = e2*inv, a3 = e3*inv;

  // alpha out via LDS transpose (tq_s reused as float[256])
  float* aT = (float*)tqb;
  { float4 av4; av4.x = a0; av4.y = a1; av4.z = a2; av4.w = a3;
    *(float4*)&aT[li*16 + gp*4] = av4; }
  { float4 o4 = *(const float4*)&aT[l*4];
    *(float4*)(out_alpha + (size_t)b*256 + l*4) = o4; }

  // ov[i] = sum_j alpha[i][j] * vv[j]
  float4 vq4 = *(const float4*)&vvl_s[wid][gp*4];
  float ovp = a0*vq4.x + a1*vq4.y + a2*vq4.z + a3*vq4.w;
  ovp += __shfl_xor(ovp, 16); ovp += __shfl_xor(ovp, 32);
  if (l < 16) ovl_s[wid][l] = ovp;

  // epilogue: out_x += ov[j]  (lane l covers t = l*4..l*4+3, j = (l&3)*4+c)
  {
    float4 ov4 = *(const float4*)&ovl_s[wid][(l & 3) * 4];
    x4.x += ov4.x; x4.y += ov4.y; x4.z += ov4.z; x4.w += ov4.w;
    *(float4*)(out_x + (size_t)b * 256 + l * 4) = x4;
  }
}

// ---------------------------------------------------------------------------
extern "C" void kernel_launch(void* const* d_in, const int* in_sizes, int n_in,
                              void* d_out, int out_size, void* d_ws, size_t ws_size,
                              hipStream_t stream)
{
  const float* obs      = (const float*)d_in[0];
  const float* policies = (const float*)d_in[1];
  const float* actions  = (const float*)d_in[2];
  const float* weights  = (const float*)d_in[3];
  const float* noise    = (const float*)d_in[4];
  const float* Wk1  = (const float*)d_in[5];
  const float* bk1  = (const float*)d_in[6];
  const float* Wk2  = (const float*)d_in[7];
  const float* bk2  = (const float*)d_in[8];
  const float* Wq1  = (const float*)d_in[9];
  const float* bq1  = (const float*)d_in[10];
  const float* Wq2  = (const float*)d_in[11];
  const float* bq2  = (const float*)d_in[12];
  const float* Wv1  = (const float*)d_in[13];
  const float* bv1  = (const float*)d_in[14];
  const float* Wv2  = (const float*)d_in[15];
  const float* bv2  = (const float*)d_in[16];
  const float* Wval = (const float*)d_in[17];
  const float* bval = (const float*)d_in[18];

  float* out = (float*)d_out;
  float* ws  = (float*)d_ws;

  const int NODES = in_sizes[0] / 128;
  const int B = NODES / 16;

  float* out_x     = out;
  float* out_alpha = out + (size_t)NODES * 16;

  hipLaunchKernelGGL(kn_kernel, dim3(B + 4), dim3(256), 0, stream,
                     policies, actions, noise, weights, Wval, bval,
                     Wk1, Wq1, Wv1, Wk2, bk2, Wq2, bq2, Wv2, bv2,
                     ws, out_x);
  hipLaunchKernelGGL(ka_kernel, dim3(B / 4), dim3(256), 0, stream,
                     obs, bk1, bq1, bv1, ws, out_x, out_alpha);
}